// Round 2
// baseline (353.265 us; speedup 1.0000x reference)
//
#include <hip/hip_runtime.h>

#define NB 64

__global__ __launch_bounds__(256) void vr_kernel(
    const float* __restrict__ in,   // [N,2] (x, g) interleaved
    const float* __restrict__ tf,   // [64,5] (knot, r, g, b, a)
    const float* __restrict__ gt,   // [2,2]  (knot, val) x 2
    float* __restrict__ out,        // [N,4]
    int n_pts)
{
    __shared__ float s_knots[NB];
    __shared__ float s_vals[NB][4];   // float4-aligned rows -> ds_read_b128

    // Stage tables into LDS (tiny: 64*5 floats)
    for (int i = threadIdx.x; i < NB; i += blockDim.x) {
        s_knots[i]   = tf[i * 5 + 0];
        s_vals[i][0] = tf[i * 5 + 1];
        s_vals[i][1] = tf[i * 5 + 2];
        s_vals[i][2] = tf[i * 5 + 3];
        s_vals[i][3] = tf[i * 5 + 4];
    }
    // grad_table: 4 floats, uniform across threads (scalar loads, L1-hit)
    const float gk0 = gt[0], gv0 = gt[1], gk1 = gt[2], gv1 = gt[3];
    const float ginv = 1.0f / (gk1 - gk0);
    __syncthreads();

    const float2* __restrict__ in2  = (const float2*)in;
    float4* __restrict__       out4 = (float4*)out;

    const int stride = gridDim.x * blockDim.x;
    for (int i = blockIdx.x * blockDim.x + threadIdx.x; i < n_pts; i += stride) {
        float2 p = in2[i];
        const float x = p.x;
        const float g = p.y;

        // Uniform-spacing guess, then exact correction against real knots.
        // Semantics: idx = largest j in [0,62] with knots[j] <= x (0 if none).
        float fid = fminf(fmaxf(x * (float)(NB - 1), 0.0f), (float)(NB - 2));
        int idx = (int)fid;
        while (idx > 0 && x < s_knots[idx]) --idx;
        while (idx < NB - 2 && x >= s_knots[idx + 1]) ++idx;

        const float lo = s_knots[idx];
        const float hi = s_knots[idx + 1];
        float t = (x - lo) / (hi - lo);
        t = fminf(fmaxf(t, 0.0f), 1.0f);
        const float omt = 1.0f - t;

        const float4 v0 = *(const float4*)s_vals[idx];
        const float4 v1 = *(const float4*)s_vals[idx + 1];

        // Same algebraic form as reference: v0*(1-t) + v1*t
        float r = v0.x * omt + v1.x * t;
        float gg = v0.y * omt + v1.y * t;
        float b = v0.z * omt + v1.z * t;
        float a = v0.w * omt + v1.w * t;

        // gradient modulation: 2-knot lerp, clamped
        float tg = (g - gk0) * ginv;
        tg = fminf(fmaxf(tg, 0.0f), 1.0f);
        const float mod = gv0 * (1.0f - tg) + gv1 * tg;

        out4[i] = make_float4(r, gg, b, a * mod);
    }
}

extern "C" void kernel_launch(void* const* d_in, const int* in_sizes, int n_in,
                              void* d_out, int out_size, void* d_ws, size_t ws_size,
                              hipStream_t stream) {
    const float* in = (const float*)d_in[0];   // input_x [N,2]
    const float* tf = (const float*)d_in[1];   // tf_table [64,5]
    const float* gt = (const float*)d_in[2];   // grad_table [2,2]
    float* out = (float*)d_out;

    const int n_pts = in_sizes[0] / 2;         // 16777216

    const int block = 256;
    int grid = 2048;                            // grid-stride; ~32 iters/thread
    vr_kernel<<<grid, block, 0, stream>>>(in, tf, gt, out, n_pts);
}